// Round 11
// baseline (456.925 us; speedup 1.0000x reference)
//
#include <hip/hip_runtime.h>

#define N_NODES 50000
#define N_EDGES 1600000
#define HD 64    // H*D
#define NH 8     // heads
#define NBKT 196 // dst buckets (dst >> 8)
#define EPB 8192 // edges per block in binning passes
#define GB1 196  // ceil(N_EDGES / EPB)
#define SCAN_M (NBKT * GB1)   // 38416
#define NB2 151               // ceil(SCAN_M / 256)
#define DCAP 8960             // pass-D LDS edge capacity (mean 8192, +8.5 sigma)
#define SEGB 2048             // 256 dst-low bins x 8 src segments

__device__ inline int wave_incl_scan(int v, int lane) {
#pragma unroll
    for (int o = 1; o < 64; o <<= 1) {
        int t = __shfl_up(v, o);
        if (lane >= o) v += t;
    }
    return v;
}

// ---------------------------------------------------- CSR build (no global atomics)
__global__ __launch_bounds__(256) void histA_kernel(const int* __restrict__ dst,
                                                    int* __restrict__ offs) {
    __shared__ int hist[NBKT];
    int t = threadIdx.x;
    if (t < NBKT) hist[t] = 0;
    __syncthreads();
    int base = blockIdx.x * EPB;
#pragma unroll
    for (int k = 0; k < EPB / 256; k++) {
        int e = base + k * 256 + t;
        if (e < N_EDGES) atomicAdd(&hist[dst[e] >> 8], 1);
    }
    __syncthreads();
    if (t < NBKT) offs[t * GB1 + blockIdx.x] = hist[t];
}

// block-local exclusive scan of offs (in place); RAW block totals -> part2
__global__ __launch_bounds__(256) void scanB1_kernel(int* __restrict__ offs,
                                                     int* __restrict__ part2) {
    __shared__ int wsum[4];
    int t = threadIdx.x, lane = t & 63, wv = t >> 6;
    int i = blockIdx.x * 256 + t;
    int v = (i < SCAN_M) ? offs[i] : 0;
    int inc = wave_incl_scan(v, lane);
    if (lane == 63) wsum[wv] = inc;
    __syncthreads();
    if (t == 0) {
        int a = 0;
        for (int k = 0; k < 4; k++) { int x = wsum[k]; wsum[k] = a; a += x; }
    }
    __syncthreads();
    int excl = wsum[wv] + inc - v;
    if (i < SCAN_M) offs[i] = excl;
    if (t == 255) part2[blockIdx.x] = wsum[wv] + inc;
}

// helper: exclusive-scan the NB2 raw totals into LDS ps[] (redundant per block)
__device__ inline void scan_part2_lds(const int* __restrict__ part2, int* ps,
                                      int* wsum, int t, int nwaves) {
    int lane = t & 63, wv = t >> 6;
    int v = (t < NB2) ? part2[t] : 0;
    int inc = wave_incl_scan(v, lane);
    if (lane == 63) wsum[wv] = inc;
    __syncthreads();
    if (t == 0) {
        int a = 0;
        for (int k = 0; k < nwaves; k++) { int x = wsum[k]; wsum[k] = a; a += x; }
    }
    __syncthreads();
    if (t < NB2) ps[t] = wsum[wv] + inc - v;
    __syncthreads();
}

__global__ __launch_bounds__(256) void scatC_kernel(const int* __restrict__ src,
                                                    const int* __restrict__ dst,
                                                    const int* __restrict__ offs,
                                                    const int* __restrict__ part2,
                                                    unsigned* __restrict__ ebuf) {
    __shared__ int cur[NBKT];
    __shared__ int base_s[NBKT];
    __shared__ int ps[NB2];
    __shared__ int wsum[4];
    int t = threadIdx.x;
    scan_part2_lds(part2, ps, wsum, t, 4);
    if (t < NBKT) {
        int f = t * GB1 + blockIdx.x;
        cur[t] = 0;
        base_s[t] = offs[f] + ps[f >> 8];
    }
    __syncthreads();
    int base = blockIdx.x * EPB;
#pragma unroll
    for (int k = 0; k < EPB / 256; k++) {
        int e = base + k * 256 + t;
        if (e < N_EDGES) {
            int d = dst[e];
            int b = d >> 8;
            int r = atomicAdd(&cur[b], 1);
            ebuf[base_s[b] + r] = (unsigned)src[e] | ((unsigned)(d & 255) << 16);
        }
    }
}

__global__ __launch_bounds__(512) void csrD_kernel(const int* __restrict__ offs,
                                                   const int* __restrict__ part2,
                                                   const unsigned* __restrict__ ebuf,
                                                   int* __restrict__ rowptr,
                                                   unsigned short* __restrict__ csr) {
    __shared__ unsigned eb[DCAP];
    __shared__ int hist[SEGB];
    __shared__ int ps[NB2];
    __shared__ int wsum[8];
    int b = blockIdx.x, t = threadIdx.x;
    scan_part2_lds(part2, ps, wsum, t, 8);
    int f0 = b * GB1;
    int base = offs[f0] + ps[f0 >> 8];
    int nxt;
    if (b == NBKT - 1) nxt = N_EDGES;
    else { int f1 = (b + 1) * GB1; nxt = offs[f1] + ps[f1 >> 8]; }
    int nb = nxt - base;
    if (nb > DCAP) nb = DCAP;  // statistically impossible; guards LDS OOB
    for (int i = t; i < SEGB; i += 512) hist[i] = 0;
    __syncthreads();
    for (int i = t; i < nb; i += 512) {
        unsigned v = ebuf[base + i];
        eb[i] = v;
        int bin = (int)((v >> 16) << 3) | (int)((v & 0xFFFFu) >> 13);
        atomicAdd(&hist[bin], 1);
    }
    __syncthreads();
    int lane = t & 63, wv = t >> 6;
    int b0 = t << 2;
    int loc0 = hist[b0], loc1 = hist[b0 + 1], loc2 = hist[b0 + 2], loc3 = hist[b0 + 3];
    int s = loc0 + loc1 + loc2 + loc3;
    int inc = wave_incl_scan(s, lane);
    if (lane == 63) wsum[wv] = inc;
    __syncthreads();
    if (t == 0) {
        int a = 0;
        for (int k = 0; k < 8; k++) { int x = wsum[k]; wsum[k] = a; a += x; }
    }
    __syncthreads();
    int run = wsum[wv] + inc - s;
    hist[b0] = run; run += loc0;
    hist[b0 + 1] = run; run += loc1;
    hist[b0 + 2] = run; run += loc2;
    hist[b0 + 3] = run;
    __syncthreads();
    if (t < 256) {
        int node = b * 256 + t;
        if (node < N_NODES) rowptr[node] = base + hist[t << 3];
    }
    if (b == 0 && t == 0) rowptr[N_NODES] = N_EDGES;
    __syncthreads();
    for (int i = t; i < nb; i += 512) {
        unsigned v = eb[i];
        int bin = (int)((v >> 16) << 3) | (int)((v & 0xFFFFu) >> 13);
        int r = atomicAdd(&hist[bin], 1);
        csr[base + r] = (unsigned short)(v & 0xFFFFu);
    }
}

// ------------------------------------------------- GEMM + attention logits
// Block = 64 nodes. x tile staged ONCE into LDS (coalesced float4, stride
// F+4 keeps 16 B alignment). Thread = (node n = t&63, feat-group fg = t>>6:
// 16 feats = 2 complete heads -> in-lane es/ed). Inner loop: ds_read_b128
// for x (short LDS latency) + wave-uniform W s_loads. x read from HBM once.
template <int F>
__global__ __launch_bounds__(256) void gemm_att_kernel(
    const float* __restrict__ x, const float* __restrict__ W,
    const float* __restrict__ att,
    _Float16* __restrict__ h, float* __restrict__ es, float* __restrict__ ed) {
    constexpr int FP = F + 4;
    __shared__ float xs[64 * FP];
    int t = threadIdx.x;
    int node0 = blockIdx.x * 64;
    constexpr int ITEMS = F * 16;  // 64 rows * F/4 float4s
#pragma unroll
    for (int i = t; i < ITEMS; i += 256) {
        int row = i / (F / 4), cb = i % (F / 4);
        int nr = node0 + row;
        if (nr >= N_NODES) nr = N_NODES - 1;
        float4 v = ((const float4*)x)[(size_t)nr * (F / 4) + cb];
        *(float4*)&xs[row * FP + cb * 4] = v;
    }
    __syncthreads();

    int n = t & 63, fg = t >> 6;
    int f0 = fg * 16;
    const float4* xr = (const float4*)&xs[n * FP];
    float acc[16];
#pragma unroll
    for (int i = 0; i < 16; i++) acc[i] = 0.f;
#pragma unroll 4
    for (int kk = 0; kk < F / 4; kk++) {
        float4 xv = xr[kk];
        const float* Wk = W + kk * 256 + f0;  // wave-uniform base -> s_load
#pragma unroll
        for (int i = 0; i < 16; i++)
            acc[i] += xv.x * Wk[i] + xv.y * Wk[64 + i] +
                      xv.z * Wk[128 + i] + xv.w * Wk[192 + i];
    }
    int node = node0 + n;
    if (node >= N_NODES) return;

    int hh = f0 >> 3;
#pragma unroll
    for (int hi = 0; hi < 2; hi++) {
        float sv = 0.f, dv = 0.f;
#pragma unroll
        for (int i = 0; i < 8; i++) {
            sv += acc[8 * hi + i] * att[f0 + 8 * hi + i];
            dv += acc[8 * hi + i] * att[64 + f0 + 8 * hi + i];
        }
        es[node * NH + hh + hi] = sv;
        ed[node * NH + hh + hi] = dv;
    }

    union { _Float16 hf[16]; uint4 u[2]; } cv;
#pragma unroll
    for (int i = 0; i < 16; i++) cv.hf[i] = (_Float16)acc[i];
    uint4* hp = (uint4*)(h + (size_t)node * HD + f0);
    hp[0] = cv.u[0];
    hp[1] = cv.u[1];
}

// ------------------------------------------------------------- aggregation
// R7 version (best measured). Wave per dst node. g=L>>3 edge subgroup,
// o=L&7 = complete head (16 B uint4 of the 1-line 128 B h row).
__global__ __launch_bounds__(256) void agg_kernel(
    const uint4* __restrict__ h8, const float* __restrict__ es,
    const float* __restrict__ ed, const int* __restrict__ rowptr,
    const unsigned short* __restrict__ csr, const float4* __restrict__ b4,
    float4* __restrict__ out4, int apply_elu) {
    int t = threadIdx.x;
    int wv = t >> 6, L = t & 63;
    int n = blockIdx.x * 4 + wv;
    if (n >= N_NODES) return;
    int g = L >> 3, o = L & 7;
    int beg = rowptr[n], end = rowptr[n + 1];
    float edn = ed[n * NH + o];
    float acc[8] = {0.f, 0.f, 0.f, 0.f, 0.f, 0.f, 0.f, 0.f};
    float ssum = 0.f;
    int j = beg;
    for (; j + 16 <= end; j += 16) {
        int s0 = csr[j + g];
        int s1 = csr[j + 8 + g];
        uint4 hv0 = h8[s0 * 8 + o];
        uint4 hv1 = h8[s1 * 8 + o];
        float ev0 = es[s0 * NH + o];
        float ev1 = es[s1 * NH + o];
        float e0 = ev0 + edn; e0 = (e0 > 0.f) ? e0 : 0.2f * e0;
        float e1 = ev1 + edn; e1 = (e1 > 0.f) ? e1 : 0.2f * e1;
        float w0 = __expf(e0), w1 = __expf(e1);
        union { uint4 u; _Float16 f[8]; } c0, c1;
        c0.u = hv0; c1.u = hv1;
#pragma unroll
        for (int i = 0; i < 8; i++)
            acc[i] += w0 * (float)c0.f[i] + w1 * (float)c1.f[i];
        ssum += w0 + w1;
    }
    for (; j < end; j += 8) {
        int idx = j + g;
        int s0 = csr[(idx < end) ? idx : (end - 1)];
        float vmask = (idx < end) ? 1.f : 0.f;
        uint4 hv0 = h8[s0 * 8 + o];
        float ev0 = es[s0 * NH + o];
        float e0 = ev0 + edn; e0 = (e0 > 0.f) ? e0 : 0.2f * e0;
        float w0 = vmask * __expf(e0);
        union { uint4 u; _Float16 f[8]; } c0; c0.u = hv0;
#pragma unroll
        for (int i = 0; i < 8; i++) acc[i] += w0 * (float)c0.f[i];
        ssum += w0;
    }
#pragma unroll
    for (int i = 0; i < 8; i++) {
        acc[i] += __shfl_xor(acc[i], 8);
        acc[i] += __shfl_xor(acc[i], 16);
        acc[i] += __shfl_xor(acc[i], 32);
    }
    ssum += __shfl_xor(ssum, 8);
    ssum += __shfl_xor(ssum, 16);
    ssum += __shfl_xor(ssum, 32);

    if (g == 0) {
        float inv = 1.f / (ssum + 1e-16f);
        float4 bv0 = b4[2 * o], bv1 = b4[2 * o + 1];
        float4 r0, r1;
        r0.x = acc[0] * inv + bv0.x; r0.y = acc[1] * inv + bv0.y;
        r0.z = acc[2] * inv + bv0.z; r0.w = acc[3] * inv + bv0.w;
        r1.x = acc[4] * inv + bv1.x; r1.y = acc[5] * inv + bv1.y;
        r1.z = acc[6] * inv + bv1.z; r1.w = acc[7] * inv + bv1.w;
        if (apply_elu) {
            r0.x = (r0.x > 0.f) ? r0.x : (__expf(r0.x) - 1.f);
            r0.y = (r0.y > 0.f) ? r0.y : (__expf(r0.y) - 1.f);
            r0.z = (r0.z > 0.f) ? r0.z : (__expf(r0.z) - 1.f);
            r0.w = (r0.w > 0.f) ? r0.w : (__expf(r0.w) - 1.f);
            r1.x = (r1.x > 0.f) ? r1.x : (__expf(r1.x) - 1.f);
            r1.y = (r1.y > 0.f) ? r1.y : (__expf(r1.y) - 1.f);
            r1.z = (r1.z > 0.f) ? r1.z : (__expf(r1.z) - 1.f);
            r1.w = (r1.w > 0.f) ? r1.w : (__expf(r1.w) - 1.f);
        }
        out4[n * 16 + 2 * o] = r0;
        out4[n * 16 + 2 * o + 1] = r1;
    }
}

// ---------------------------------------------------------------- launcher
extern "C" void kernel_launch(void* const* d_in, const int* in_sizes, int n_in,
                              void* d_out, int out_size, void* d_ws, size_t ws_size,
                              hipStream_t stream) {
    const float* x   = (const float*)d_in[0];
    const int*   ei  = (const int*)d_in[1];
    const int*   src = ei;
    const int*   dst = ei + N_EDGES;
    const float* W[4]   = {(const float*)d_in[2], (const float*)d_in[5],
                           (const float*)d_in[8], (const float*)d_in[11]};
    const float* att[4] = {(const float*)d_in[3], (const float*)d_in[6],
                           (const float*)d_in[9], (const float*)d_in[12]};
    const float* bb[4]  = {(const float*)d_in[4], (const float*)d_in[7],
                           (const float*)d_in[10], (const float*)d_in[13]};

    char* wsb = (char*)d_ws;
    size_t off = 0;
    auto alloc = [&](size_t bytes) -> void* {
        size_t a = (off + 255) & ~(size_t)255;
        off = a + bytes;
        return (void*)(wsb + a);
    };
    int*            offs   = (int*)alloc((size_t)SCAN_M * 4);
    int*            part2  = (int*)alloc((size_t)NB2 * 4);
    unsigned*       ebuf   = (unsigned*)alloc((size_t)N_EDGES * 4);
    int*            rowptr = (int*)alloc((size_t)(N_NODES + 1) * 4);
    unsigned short* csr    = (unsigned short*)alloc((size_t)N_EDGES * 2);
    _Float16*       h      = (_Float16*)alloc((size_t)N_NODES * HD * 2);
    float*          es     = (float*)alloc((size_t)N_NODES * NH * 4);
    float*          ed     = (float*)alloc((size_t)N_NODES * NH * 4);
    float*          act0   = (float*)alloc((size_t)N_NODES * HD * 4);
    float*          act1   = (float*)alloc((size_t)N_NODES * HD * 4);

    // CSR build — all atomics in LDS; part2 scan folded into consumers
    histA_kernel<<<GB1, 256, 0, stream>>>(dst, offs);
    scanB1_kernel<<<NB2, 256, 0, stream>>>(offs, part2);
    scatC_kernel<<<GB1, 256, 0, stream>>>(src, dst, offs, part2, ebuf);
    csrD_kernel<<<NBKT, 512, 0, stream>>>(offs, part2, ebuf, rowptr, csr);

    const int GGX = (N_NODES + 63) / 64;  // 782 blocks, 64 nodes each
    const int GA  = N_NODES / 4;          // 12500

    gemm_att_kernel<128><<<GGX, 256, 0, stream>>>(x, W[0], att[0], h, es, ed);
    agg_kernel<<<GA, 256, 0, stream>>>((const uint4*)h, es, ed, rowptr, csr,
                                       (const float4*)bb[0], (float4*)act0, 1);
    gemm_att_kernel<64><<<GGX, 256, 0, stream>>>(act0, W[1], att[1], h, es, ed);
    agg_kernel<<<GA, 256, 0, stream>>>((const uint4*)h, es, ed, rowptr, csr,
                                       (const float4*)bb[1], (float4*)act1, 1);
    gemm_att_kernel<64><<<GGX, 256, 0, stream>>>(act1, W[2], att[2], h, es, ed);
    agg_kernel<<<GA, 256, 0, stream>>>((const uint4*)h, es, ed, rowptr, csr,
                                       (const float4*)bb[2], (float4*)act0, 1);
    gemm_att_kernel<64><<<GGX, 256, 0, stream>>>(act0, W[3], att[3], h, es, ed);
    agg_kernel<<<GA, 256, 0, stream>>>((const uint4*)h, es, ed, rowptr, csr,
                                       (const float4*)bb[3], (float4*)d_out, 0);
}

// Round 12
// 363.873 us; speedup vs baseline: 1.2557x; 1.2557x over previous
//
#include <hip/hip_runtime.h>

#define N_NODES 50000
#define N_EDGES 1600000
#define HD 64    // H*D
#define NH 8     // heads
#define NBKT 196 // dst buckets (dst >> 8)
#define EPB 8192 // edges per block in binning passes
#define GB1 196  // ceil(N_EDGES / EPB)
#define SCAN_M (NBKT * GB1)   // 38416
#define NB2 151               // ceil(SCAN_M / 256)
#define DCAP 8960             // pass-D LDS edge capacity (mean 8192, +8.5 sigma)
#define SEGB 2048             // 256 dst-low bins x 8 src segments

__device__ inline int wave_incl_scan(int v, int lane) {
#pragma unroll
    for (int o = 1; o < 64; o <<= 1) {
        int t = __shfl_up(v, o);
        if (lane >= o) v += t;
    }
    return v;
}

// ---------------------------------------------------- CSR build (no global atomics)
__global__ __launch_bounds__(256) void histA_kernel(const int* __restrict__ dst,
                                                    int* __restrict__ offs) {
    __shared__ int hist[NBKT];
    int t = threadIdx.x;
    if (t < NBKT) hist[t] = 0;
    __syncthreads();
    int base = blockIdx.x * EPB;
#pragma unroll
    for (int k = 0; k < EPB / 256; k++) {
        int e = base + k * 256 + t;
        if (e < N_EDGES) atomicAdd(&hist[dst[e] >> 8], 1);
    }
    __syncthreads();
    if (t < NBKT) offs[t * GB1 + blockIdx.x] = hist[t];
}

__global__ __launch_bounds__(256) void scanB1_kernel(int* __restrict__ offs,
                                                     int* __restrict__ part2) {
    __shared__ int wsum[4];
    int t = threadIdx.x, lane = t & 63, wv = t >> 6;
    int i = blockIdx.x * 256 + t;
    int v = (i < SCAN_M) ? offs[i] : 0;
    int inc = wave_incl_scan(v, lane);
    if (lane == 63) wsum[wv] = inc;
    __syncthreads();
    if (t == 0) {
        int a = 0;
        for (int k = 0; k < 4; k++) { int x = wsum[k]; wsum[k] = a; a += x; }
    }
    __syncthreads();
    int excl = wsum[wv] + inc - v;
    if (i < SCAN_M) offs[i] = excl;
    if (t == 255) part2[blockIdx.x] = wsum[wv] + inc;
}

__global__ __launch_bounds__(256) void scanB2_kernel(int* __restrict__ part2) {
    __shared__ int wsum[4];
    int t = threadIdx.x, lane = t & 63, wv = t >> 6;
    int v = (t < NB2) ? part2[t] : 0;
    int inc = wave_incl_scan(v, lane);
    if (lane == 63) wsum[wv] = inc;
    __syncthreads();
    if (t == 0) {
        int a = 0;
        for (int k = 0; k < 4; k++) { int x = wsum[k]; wsum[k] = a; a += x; }
    }
    __syncthreads();
    if (t < NB2) part2[t] = wsum[wv] + inc - v;
}

__global__ __launch_bounds__(256) void scatC_kernel(const int* __restrict__ src,
                                                    const int* __restrict__ dst,
                                                    const int* __restrict__ offs,
                                                    const int* __restrict__ part2,
                                                    unsigned* __restrict__ ebuf) {
    __shared__ int cur[NBKT];
    __shared__ int base_s[NBKT];
    int t = threadIdx.x;
    if (t < NBKT) {
        int f = t * GB1 + blockIdx.x;
        cur[t] = 0;
        base_s[t] = offs[f] + part2[f >> 8];
    }
    __syncthreads();
    int base = blockIdx.x * EPB;
#pragma unroll
    for (int k = 0; k < EPB / 256; k++) {
        int e = base + k * 256 + t;
        if (e < N_EDGES) {
            int d = dst[e];
            int b = d >> 8;
            int r = atomicAdd(&cur[b], 1);
            ebuf[base_s[b] + r] = (unsigned)src[e] | ((unsigned)(d & 255) << 16);
        }
    }
}

__global__ __launch_bounds__(512) void csrD_kernel(const int* __restrict__ offs,
                                                   const int* __restrict__ part2,
                                                   const unsigned* __restrict__ ebuf,
                                                   int* __restrict__ rowptr,
                                                   unsigned short* __restrict__ csr) {
    __shared__ unsigned eb[DCAP];
    __shared__ int hist[SEGB];
    __shared__ int wsum[8];
    int b = blockIdx.x, t = threadIdx.x;
    int f0 = b * GB1;
    int base = offs[f0] + part2[f0 >> 8];
    int nxt;
    if (b == NBKT - 1) nxt = N_EDGES;
    else { int f1 = (b + 1) * GB1; nxt = offs[f1] + part2[f1 >> 8]; }
    int nb = nxt - base;
    if (nb > DCAP) nb = DCAP;  // statistically impossible; guards LDS OOB
    for (int i = t; i < SEGB; i += 512) hist[i] = 0;
    __syncthreads();
    for (int i = t; i < nb; i += 512) {
        unsigned v = ebuf[base + i];
        eb[i] = v;
        int bin = (int)((v >> 16) << 3) | (int)((v & 0xFFFFu) >> 13);
        atomicAdd(&hist[bin], 1);
    }
    __syncthreads();
    int lane = t & 63, wv = t >> 6;
    int b0 = t << 2;
    int loc0 = hist[b0], loc1 = hist[b0 + 1], loc2 = hist[b0 + 2], loc3 = hist[b0 + 3];
    int s = loc0 + loc1 + loc2 + loc3;
    int inc = wave_incl_scan(s, lane);
    if (lane == 63) wsum[wv] = inc;
    __syncthreads();
    if (t == 0) {
        int a = 0;
        for (int k = 0; k < 8; k++) { int x = wsum[k]; wsum[k] = a; a += x; }
    }
    __syncthreads();
    int run = wsum[wv] + inc - s;
    hist[b0] = run; run += loc0;
    hist[b0 + 1] = run; run += loc1;
    hist[b0 + 2] = run; run += loc2;
    hist[b0 + 3] = run;
    __syncthreads();
    if (t < 256) {
        int node = b * 256 + t;
        if (node < N_NODES) rowptr[node] = base + hist[t << 3];
    }
    if (b == 0 && t == 0) rowptr[N_NODES] = N_EDGES;
    __syncthreads();
    for (int i = t; i < nb; i += 512) {
        unsigned v = eb[i];
        int bin = (int)((v >> 16) << 3) | (int)((v & 0xFFFFu) >> 13);
        int r = atomicAdd(&hist[bin], 1);
        csr[base + r] = (unsigned short)(v & 0xFFFFu);
    }
}

// ------------------------------------------------- GEMM + attention logits
// Thread = node; blockIdx.y picks a 16-feature block (= 2 complete heads).
// W/att indices wave-uniform -> s_load; x per-lane float4 stream.
template <int F>
__global__ __launch_bounds__(256) void gemm_att_kernel(
    const float* __restrict__ x, const float* __restrict__ W,
    const float* __restrict__ att,
    _Float16* __restrict__ h, float* __restrict__ es, float* __restrict__ ed) {
    int t = threadIdx.x;
    int n = blockIdx.x * 256 + t;
    int f0 = blockIdx.y * 16;
    int nc = (n < N_NODES) ? n : (N_NODES - 1);
    const float4* xrow = (const float4*)x + (size_t)nc * (F / 4);
    float acc[16];
#pragma unroll
    for (int i = 0; i < 16; i++) acc[i] = 0.f;
#pragma unroll 4
    for (int kk = 0; kk < F / 4; kk++) {
        float4 xv = xrow[kk];
        const float* Wk = W + (kk * 4) * 64 + f0;  // wave-uniform base
#pragma unroll
        for (int i = 0; i < 16; i++)
            acc[i] += xv.x * Wk[i] + xv.y * Wk[64 + i] +
                      xv.z * Wk[128 + i] + xv.w * Wk[192 + i];
    }
    if (n >= N_NODES) return;

    float s0 = 0.f, s1 = 0.f, d0 = 0.f, d1 = 0.f;
#pragma unroll
    for (int i = 0; i < 8; i++) {
        s0 += acc[i] * att[f0 + i];
        d0 += acc[i] * att[64 + f0 + i];
    }
#pragma unroll
    for (int i = 8; i < 16; i++) {
        s1 += acc[i] * att[f0 + i];
        d1 += acc[i] * att[64 + f0 + i];
    }
    int hh = f0 >> 3;
    es[n * NH + hh] = s0; es[n * NH + hh + 1] = s1;
    ed[n * NH + hh] = d0; ed[n * NH + hh + 1] = d1;

    union { _Float16 hf[16]; uint4 u[2]; } cv;
#pragma unroll
    for (int i = 0; i < 16; i++) cv.hf[i] = (_Float16)acc[i];
    uint4* hp = (uint4*)(h + (size_t)n * HD + f0);
    hp[0] = cv.u[0];
    hp[1] = cv.u[1];
}

// ------------------------------------------------------------- aggregation
// Wave per dst node. Lane L: g=L>>3 edge subgroup (8 edges in flight per
// batch), o=L&7 = COMPLETE head (16 B uint4 of the 128 B = 1-cache-line
// h row). Per 64-lane gather instr: 8 line-requests.
__global__ __launch_bounds__(256) void agg_kernel(
    const uint4* __restrict__ h8, const float* __restrict__ es,
    const float* __restrict__ ed, const int* __restrict__ rowptr,
    const unsigned short* __restrict__ csr, const float4* __restrict__ b4,
    float4* __restrict__ out4, int apply_elu) {
    int t = threadIdx.x;
    int wv = t >> 6, L = t & 63;
    int n = blockIdx.x * 4 + wv;
    if (n >= N_NODES) return;
    int g = L >> 3, o = L & 7;
    int beg = rowptr[n], end = rowptr[n + 1];
    float edn = ed[n * NH + o];
    float acc[8] = {0.f, 0.f, 0.f, 0.f, 0.f, 0.f, 0.f, 0.f};
    float ssum = 0.f;
    int j = beg;
    for (; j + 16 <= end; j += 16) {
        int s0 = csr[j + g];
        int s1 = csr[j + 8 + g];
        uint4 hv0 = h8[s0 * 8 + o];
        uint4 hv1 = h8[s1 * 8 + o];
        float ev0 = es[s0 * NH + o];
        float ev1 = es[s1 * NH + o];
        float e0 = ev0 + edn; e0 = (e0 > 0.f) ? e0 : 0.2f * e0;
        float e1 = ev1 + edn; e1 = (e1 > 0.f) ? e1 : 0.2f * e1;
        float w0 = __expf(e0), w1 = __expf(e1);
        union { uint4 u; _Float16 f[8]; } c0, c1;
        c0.u = hv0; c1.u = hv1;
#pragma unroll
        for (int i = 0; i < 8; i++)
            acc[i] += w0 * (float)c0.f[i] + w1 * (float)c1.f[i];
        ssum += w0 + w1;
    }
    for (; j < end; j += 8) {
        int idx = j + g;
        int s0 = csr[(idx < end) ? idx : (end - 1)];
        float vmask = (idx < end) ? 1.f : 0.f;
        uint4 hv0 = h8[s0 * 8 + o];
        float ev0 = es[s0 * NH + o];
        float e0 = ev0 + edn; e0 = (e0 > 0.f) ? e0 : 0.2f * e0;
        float w0 = vmask * __expf(e0);
        union { uint4 u; _Float16 f[8]; } c0; c0.u = hv0;
#pragma unroll
        for (int i = 0; i < 8; i++) acc[i] += w0 * (float)c0.f[i];
        ssum += w0;
    }
#pragma unroll
    for (int i = 0; i < 8; i++) {
        acc[i] += __shfl_xor(acc[i], 8);
        acc[i] += __shfl_xor(acc[i], 16);
        acc[i] += __shfl_xor(acc[i], 32);
    }
    ssum += __shfl_xor(ssum, 8);
    ssum += __shfl_xor(ssum, 16);
    ssum += __shfl_xor(ssum, 32);

    if (g == 0) {
        float inv = 1.f / (ssum + 1e-16f);
        float4 bv0 = b4[2 * o], bv1 = b4[2 * o + 1];
        float4 r0, r1;
        r0.x = acc[0] * inv + bv0.x; r0.y = acc[1] * inv + bv0.y;
        r0.z = acc[2] * inv + bv0.z; r0.w = acc[3] * inv + bv0.w;
        r1.x = acc[4] * inv + bv1.x; r1.y = acc[5] * inv + bv1.y;
        r1.z = acc[6] * inv + bv1.z; r1.w = acc[7] * inv + bv1.w;
        if (apply_elu) {
            r0.x = (r0.x > 0.f) ? r0.x : (__expf(r0.x) - 1.f);
            r0.y = (r0.y > 0.f) ? r0.y : (__expf(r0.y) - 1.f);
            r0.z = (r0.z > 0.f) ? r0.z : (__expf(r0.z) - 1.f);
            r0.w = (r0.w > 0.f) ? r0.w : (__expf(r0.w) - 1.f);
            r1.x = (r1.x > 0.f) ? r1.x : (__expf(r1.x) - 1.f);
            r1.y = (r1.y > 0.f) ? r1.y : (__expf(r1.y) - 1.f);
            r1.z = (r1.z > 0.f) ? r1.z : (__expf(r1.z) - 1.f);
            r1.w = (r1.w > 0.f) ? r1.w : (__expf(r1.w) - 1.f);
        }
        out4[n * 16 + 2 * o] = r0;
        out4[n * 16 + 2 * o + 1] = r1;
    }
}

// ---------------------------------------------------------------- launcher
extern "C" void kernel_launch(void* const* d_in, const int* in_sizes, int n_in,
                              void* d_out, int out_size, void* d_ws, size_t ws_size,
                              hipStream_t stream) {
    const float* x   = (const float*)d_in[0];
    const int*   ei  = (const int*)d_in[1];
    const int*   src = ei;
    const int*   dst = ei + N_EDGES;
    const float* W[4]   = {(const float*)d_in[2], (const float*)d_in[5],
                           (const float*)d_in[8], (const float*)d_in[11]};
    const float* att[4] = {(const float*)d_in[3], (const float*)d_in[6],
                           (const float*)d_in[9], (const float*)d_in[12]};
    const float* bb[4]  = {(const float*)d_in[4], (const float*)d_in[7],
                           (const float*)d_in[10], (const float*)d_in[13]};

    char* wsb = (char*)d_ws;
    size_t off = 0;
    auto alloc = [&](size_t bytes) -> void* {
        size_t a = (off + 255) & ~(size_t)255;
        off = a + bytes;
        return (void*)(wsb + a);
    };
    int*            offs   = (int*)alloc((size_t)SCAN_M * 4);
    int*            part2  = (int*)alloc((size_t)NB2 * 4);
    unsigned*       ebuf   = (unsigned*)alloc((size_t)N_EDGES * 4);
    int*            rowptr = (int*)alloc((size_t)(N_NODES + 1) * 4);
    unsigned short* csr    = (unsigned short*)alloc((size_t)N_EDGES * 2);
    _Float16*       h      = (_Float16*)alloc((size_t)N_NODES * HD * 2);
    float*          es     = (float*)alloc((size_t)N_NODES * NH * 4);
    float*          ed     = (float*)alloc((size_t)N_NODES * NH * 4);
    float*          act0   = (float*)alloc((size_t)N_NODES * HD * 4);
    float*          act1   = (float*)alloc((size_t)N_NODES * HD * 4);

    // CSR build — all atomics in LDS, scan fully parallel
    histA_kernel<<<GB1, 256, 0, stream>>>(dst, offs);
    scanB1_kernel<<<NB2, 256, 0, stream>>>(offs, part2);
    scanB2_kernel<<<1, 256, 0, stream>>>(part2);
    scatC_kernel<<<GB1, 256, 0, stream>>>(src, dst, offs, part2, ebuf);
    csrD_kernel<<<NBKT, 512, 0, stream>>>(offs, part2, ebuf, rowptr, csr);

    const dim3 GG(196, 4);       // 196*256 = 50176 >= N_NODES; y = f-block
    const int  GA = N_NODES / 4; // 12500

    gemm_att_kernel<128><<<GG, 256, 0, stream>>>(x, W[0], att[0], h, es, ed);
    agg_kernel<<<GA, 256, 0, stream>>>((const uint4*)h, es, ed, rowptr, csr,
                                       (const float4*)bb[0], (float4*)act0, 1);
    gemm_att_kernel<64><<<GG, 256, 0, stream>>>(act0, W[1], att[1], h, es, ed);
    agg_kernel<<<GA, 256, 0, stream>>>((const uint4*)h, es, ed, rowptr, csr,
                                       (const float4*)bb[1], (float4*)act1, 1);
    gemm_att_kernel<64><<<GG, 256, 0, stream>>>(act1, W[2], att[2], h, es, ed);
    agg_kernel<<<GA, 256, 0, stream>>>((const uint4*)h, es, ed, rowptr, csr,
                                       (const float4*)bb[2], (float4*)act0, 1);
    gemm_att_kernel<64><<<GG, 256, 0, stream>>>(act0, W[3], att[3], h, es, ed);
    agg_kernel<<<GA, 256, 0, stream>>>((const uint4*)h, es, ed, rowptr, csr,
                                       (const float4*)bb[3], (float4*)d_out, 0);
}